// Round 4
// baseline (161.991 us; speedup 1.0000x reference)
//
#include <hip/hip_runtime.h>
#include <hip/hip_bf16.h>

#define B_ 128
#define F_ 100
#define N_ 512
#define H_ 1024
#define P_ 512
#define E_ 8

#define BM 128
#define BK 64
#define ROWS (B_ * F_)        // 12800 packed real rows
#define RPAD (ROWS + 128)     // staging may overrun one tile
#define MT_MAX 112            // 8 XCD groups x 14 tile slots (>= max ~107 tiles)

typedef __attribute__((ext_vector_type(8))) short bf16x8;
typedef __attribute__((ext_vector_type(4))) float f32x4;

// async global->LDS DMA, 16B/lane, LDS dest = wave-uniform base + lane*16
#define GLOAD16(g, l) __builtin_amdgcn_global_load_lds(                      \
    (const __attribute__((address_space(1))) void*)(g),                      \
    (__attribute__((address_space(3))) void*)(l), 16, 0, 0)

static __device__ __forceinline__ short f2bf(float f) {
    __hip_bfloat16 h = __float2bfloat16(f);
    short s;
    __builtin_memcpy(&s, &h, sizeof(s));
    return s;
}

// One kernel: transpose+convert W1 and W2; block (0,0,0) additionally sorts
// trials by expert and builds the M-tile table (packed rows, expert-pure tiles).
// grid (16, 16, E): y<8 -> W1 [512][1024]; y>=8 -> W2 [1024][512].
__global__ __launch_bounds__(256) void prep_weights(
    const float* __restrict__ W1, const float* __restrict__ W2,
    short* __restrict__ W1T, short* __restrict__ W2T,
    const int* __restrict__ eid, int* __restrict__ perm,
    int4* __restrict__ ttab) {
    __shared__ float tile[64][65];
    __shared__ int scnt[E_], sbase[E_];
    const int e = blockIdx.z;
    const float* W; short* WT; int R, C, c0, r0;
    if (blockIdx.y < 8) {
        W = W1; WT = W1T; R = N_; C = H_;
        c0 = blockIdx.x * 64; r0 = blockIdx.y * 64;
    } else {
        W = W2; WT = W2T; R = H_; C = P_;
        c0 = (blockIdx.x & 7) * 64;
        r0 = ((blockIdx.y - 8) * 2 + (blockIdx.x >> 3)) * 64;
    }
    const int t = threadIdx.x;
    const float* Wp = W + (size_t)e * R * C;
    short* WTp = WT + (size_t)e * C * R;
    {
        const int c4 = (t & 15) * 4, r = t >> 4;
#pragma unroll
        for (int p = 0; p < 4; p++) {
            const int row = p * 16 + r;
            const float4 v = *(const float4*)(Wp + (size_t)(r0 + row) * C + c0 + c4);
            tile[row][c4 + 0] = v.x; tile[row][c4 + 1] = v.y;
            tile[row][c4 + 2] = v.z; tile[row][c4 + 3] = v.w;
        }
    }
    __syncthreads();
    {
        const int r8 = (t & 7) * 8, cl = t >> 3;
#pragma unroll
        for (int p = 0; p < 2; p++) {
            const int c = p * 32 + cl;
            union { short s[8]; uint4 u; } o;
#pragma unroll
            for (int j = 0; j < 8; j++) o.s[j] = f2bf(tile[r8 + j][c]);
            *(uint4*)(&WTp[(size_t)(c0 + c) * R + r0 + r8]) = o.u;
        }
    }
    // ---- trial sort + tile table (block (0,0,0) only) ----
    if (blockIdx.x == 0 && blockIdx.y == 0 && blockIdx.z == 0) {
        __syncthreads();
        if (t < E_) scnt[t] = 0;
        __syncthreads();
        int my_e = 0;
        if (t < B_) { my_e = eid[t]; atomicAdd(&scnt[my_e], 1); }
        __syncthreads();
        if (t == 0) {
            int s = 0;
            for (int i = 0; i < E_; i++) { sbase[i] = s; s += scnt[i]; }
        }
        __syncthreads();
        if (t < B_) {
            const int pos = atomicAdd(&sbase[my_e], 1);
            perm[pos] = t;
        }
        if (t == 0) {
            int tix = 0, s = 0;
            for (int e2 = 0; e2 < E_; e2++) {
                const int c = scnt[e2];
                const int r1 = (s + c) * F_;
                for (int m0 = s * F_; m0 < r1; m0 += BM)
                    ttab[tix++] = make_int4(m0, min(m0 + BM, r1), e2, 0);
                s += c;
            }
            for (; tix < MT_MAX; tix++) ttab[tix] = make_int4(1 << 30, 0, 0, 0);
        }
    }
}

// x [B][F][N] fp32 -> xs [ROWS][N] bf16, packed in sorted-trial order.
// Block swizzle so the writing XCD ~matches the GEMM1 reading XCD.
__global__ __launch_bounds__(256) void convert_x(const float* __restrict__ x,
                                                 const int* __restrict__ perm,
                                                 short* __restrict__ xs) {
    const int gs = (blockIdx.x & 7) * 400 + (blockIdx.x >> 3);
    const int g = gs * 256 + threadIdx.x;       // one 8-elem chunk
    const int col = (g & (N_ / 8 - 1)) * 8;
    const int row = g >> 6;                     // packed row, 0..12799
    const int sp = row / F_, f = row % F_;
    const int b = perm[sp];
    const float* xp = x + ((size_t)(b * F_ + f)) * N_ + col;
    const float4 v0 = *(const float4*)(xp);
    const float4 v1 = *(const float4*)(xp + 4);
    union { short s[8]; uint4 u; } o;
    o.s[0] = f2bf(v0.x); o.s[1] = f2bf(v0.y);
    o.s[2] = f2bf(v0.z); o.s[3] = f2bf(v0.w);
    o.s[4] = f2bf(v1.x); o.s[5] = f2bf(v1.y);
    o.s[6] = f2bf(v1.z); o.s[7] = f2bf(v1.w);
    *(uint4*)(xs + (size_t)row * N_ + col) = o.u;
}

// 128xBN_ tile GEMM over PACKED sorted rows. BK=64, 4 waves (2x2),
// mfma_f32_16x16x32_bf16, async global_load_lds with XOR-swizzled LDS
// (swizzle applied to the GLOBAL address; DMA LDS dest is base+lane*16).
// Tile table gives (m0, m_end, expert) per block; XCD r owns tile slots
// [14r,14r+14) -> contiguous expert rows per XCD L2.
// FIRST:  act[m][col] = softsign(A @ W1T^T + b1), bf16 packed [ROWS][H]
// !FIRST: out = A @ W2T^T + b2 -> fp32 scattered to out[perm[m/F]][m%F][col]
template <int KDIM, int BN_, bool FIRST>
__global__ __launch_bounds__(256, 4) void gemm_kernel(
    const short* __restrict__ A,     // [RPAD][KDIM] bf16 packed, K-contig
    const short* __restrict__ WT,    // [E][NCOLS][KDIM] bf16, K-contig
    const float* __restrict__ bias,  // [E][NCOLS]
    const int* __restrict__ perm,    // [B] sorted -> original trial
    const int4* __restrict__ ttab,   // [MT_MAX] (m0, m_end, e, -)
    short* __restrict__ actout,      // FIRST
    float* __restrict__ out)         // !FIRST
{
    constexpr int NCOLS = FIRST ? H_ : P_;
    constexpr int NI = BN_ / 32;
    __shared__ short sA[BM * BK];
    __shared__ short sB[BN_ * BK];
    const int xt = (blockIdx.x & 7) * 14 + (blockIdx.x >> 3);
    const int4 tt = ttab[xt];
    if (tt.x >= ROWS) return;
    const int m0 = tt.x, me = tt.y, e = tt.z;
    const int n0 = blockIdx.y * BN_;
    const int t = threadIdx.x;
    const int lane = t & 63, w = t >> 6;
    const int wm = (w >> 1) * 64, wn = (w & 1) * (BN_ / 2);
    const int l15 = lane & 15, quad = lane >> 4;
    const int lr = lane >> 3;                 // staging row 0..7
    const int lc = (((lane & 7) ^ lr) * 8);   // XOR-swizzled col chunk

    f32x4 acc[4][NI];
#pragma unroll
    for (int mi = 0; mi < 4; mi++)
#pragma unroll
        for (int ni = 0; ni < NI; ni++)
            acc[mi][ni] = (f32x4)(0.0f);

    const short* Ap = A + (size_t)m0 * KDIM;
    const short* Bp = WT + ((size_t)e * NCOLS + n0) * KDIM;

    for (int k0 = 0; k0 < KDIM; k0 += BK) {
#pragma unroll
        for (int i = 0; i < 4; i++) {
            const int rb = w * 32 + i * 8;
            GLOAD16(Ap + (size_t)(rb + lr) * KDIM + k0 + lc, &sA[rb * BK]);
        }
#pragma unroll
        for (int i = 0; i < BN_ / 32; i++) {
            const int rb = w * (BN_ / 4) + i * 8;
            GLOAD16(Bp + (size_t)(rb + lr) * KDIM + k0 + lc, &sB[rb * BK]);
        }
        __syncthreads();
#pragma unroll
        for (int ks = 0; ks < 2; ks++) {
            bf16x8 af[4], bfr[NI];
#pragma unroll
            for (int mi = 0; mi < 4; mi++) {
                const int ra = wm + mi * 16 + l15;
                af[mi] = *(const bf16x8*)(&sA[ra * BK + (((ks * 4 + quad) ^ (ra & 7)) * 8)]);
            }
#pragma unroll
            for (int ni = 0; ni < NI; ni++) {
                const int rbn = wn + ni * 16 + l15;
                bfr[ni] = *(const bf16x8*)(&sB[rbn * BK + (((ks * 4 + quad) ^ (rbn & 7)) * 8)]);
            }
#pragma unroll
            for (int mi = 0; mi < 4; mi++)
#pragma unroll
                for (int ni = 0; ni < NI; ni++)
                    acc[mi][ni] = __builtin_amdgcn_mfma_f32_16x16x32_bf16(af[mi], bfr[ni], acc[mi][ni], 0, 0, 0);
        }
        __syncthreads();
    }

    // epilogue: C/D layout col=lane&15, row=quad*4+reg
#pragma unroll
    for (int mi = 0; mi < 4; mi++) {
#pragma unroll
        for (int ni = 0; ni < NI; ni++) {
            const int col = n0 + wn + ni * 16 + l15;
            const float bv = bias[(size_t)e * NCOLS + col];
#pragma unroll
            for (int r = 0; r < 4; r++) {
                const int grow = m0 + wm + mi * 16 + quad * 4 + r;
                if (grow < me) {
                    float v = acc[mi][ni][r] + bv;
                    if constexpr (FIRST) {
                        v = v / (1.0f + fabsf(v));  // softsign, SCALE=1
                        actout[(size_t)grow * H_ + col] = f2bf(v);
                    } else {
                        const int sp = grow / F_, f = grow % F_;
                        out[((size_t)perm[sp] * F_ + f) * P_ + col] = v;
                    }
                }
            }
        }
    }
}

extern "C" void kernel_launch(void* const* d_in, const int* in_sizes, int n_in,
                              void* d_out, int out_size, void* d_ws, size_t ws_size,
                              hipStream_t stream) {
    const float* x  = (const float*)d_in[0];
    const int* eid  = (const int*)d_in[1];
    const float* W1 = (const float*)d_in[2];
    const float* b1 = (const float*)d_in[3];
    const float* W2 = (const float*)d_in[4];
    const float* b2 = (const float*)d_in[5];
    float* out = (float*)d_out;

    char* ws = (char*)d_ws;
    short* W1T = (short*)(ws);                          // [E][H][N]    8 MiB
    short* W2T = (short*)(ws + (size_t)(8u << 20));     // [E][P][H]    8 MiB
    short* act = (short*)(ws + (size_t)(16u << 20));    // [RPAD][H]   ~26 MiB
    short* xs  = (short*)(ws + (size_t)(44u << 20));    // [RPAD][N]   ~13 MiB
    int*  perm = (int*)(ws + (size_t)(58u << 20));      // [B]
    int4* ttab = (int4*)(ws + (size_t)(58u << 20) + 1024);  // [MT_MAX]

    prep_weights<<<dim3(16, 16, E_), 256, 0, stream>>>(W1, W2, W1T, W2T, eid, perm, ttab);
    convert_x<<<dim3(ROWS * N_ / 8 / 256), 256, 0, stream>>>(x, perm, xs);
    gemm_kernel<N_, 128, true><<<dim3(MT_MAX, H_ / 128), 256, 0, stream>>>(xs, W1T, b1, perm, ttab, act, nullptr);
    gemm_kernel<H_, 64, false><<<dim3(MT_MAX, P_ / 64), 256, 0, stream>>>(act, W2T, b2, perm, ttab, nullptr, out);
}